// Round 9
// baseline (124.945 us; speedup 1.0000x reference)
//
#include <hip/hip_runtime.h>
#include <hip/hip_bf16.h>
#include <math.h>

// Fused ConvTranspose2d(64->64,k4,s2,p1) + BN + softmax(C) + maxpool2x2 via bf16 MFMA.
//
// R16: barrier elimination (R15: ~38us fused, 11 __syncthreads/block, 8 of
// them in the ks loop each draining vmcnt+lgkm across 8 waves every ~400cy).
//  - per-wave REGISTER weights (1-deep ping-pong bfA/bfB) instead of LDS
//    wbuf: drops all 8 in-loop barriers and all bf ds_reads. L2 weight
//    traffic 128->256MB (no wave-pair sharing) but fully latency-hidden:
//    16 MFMAs/ks (~310cy) > L2 latency (~225cy).
//  - register headroom from address folding: mt offset (+2048B) and
//    prow/a row offsets (+8448B) are compile-time ds_read immediates
//    (mt*16 cols == 0 mod 8 leaves the XOR chunk unchanged), so a-frag
//    addressing needs only A2[b][par] = 4 base regs (was 8).
//    acc 64 + bf 32 + af 16 + addr 4 + misc ~= 124 <= 128 at (512,4).
//  - red[2][64][65] in its OWN buffer (zeroed under the staging barrier);
//    post-loop waves go straight to softmax+atomics. Barriers 11 -> 2.
//    LDS = 33792(xs) + 33344(red) = 67136 -> 2 blocks/CU.
// Kept: 2 pooled rows/block, class-per-wave, pitch-65 ds_max_u32 pooling,
// XCD-grouping swizzle, BN bias as MFMA C-in, log2e in weights, padded
// 66-col halo, DPP 16-lane softmax reduce, v_cvt_pk_bf16_f32 staging.

typedef __attribute__((ext_vector_type(8))) short short8;
typedef __attribute__((ext_vector_type(4))) float floatx4;
typedef __attribute__((ext_vector_type(2))) unsigned uint2v;

__device__ ushort g_wfrag[4 * 8 * 4 * 64 * 8];  // [class][ks][nt][lane][j], 128 KB
__device__ float g_aff[64];  // ((bias-mean)*A + beta) * log2e

#define L2E 1.44269504088896340736f

__device__ __forceinline__ ushort f2bf(float f) {
  union { float f; unsigned u; } v; v.f = f;
  unsigned r = v.u + 0x7FFF + ((v.u >> 16) & 1);  // RNE
  return (ushort)(r >> 16);
}

// prep: thread = (cin pair, cout). BN scale A and log2(e) folded into weights.
__global__ __launch_bounds__(256) void prep_kernel(
    const float* __restrict__ w, const float* __restrict__ bias,
    const float* __restrict__ gamma, const float* __restrict__ beta,
    const float* __restrict__ mean, const float* __restrict__ var) {
  int t = blockIdx.x * 256 + threadIdx.x;  // 0..2047
  int cin0 = (t >> 6) * 2;                 // even cin
  int cout = t & 63;
  int nt = cout >> 4, b15 = cout & 15;
  int q = (cin0 & 31) >> 3;                // quad within k-step
  int j = cin0 & 7;                        // j within quad (even)
  int ksq = cin0 >> 5;                     // which 32-block within tap
  float Aw = gamma[cout] * rsqrtf(var[cout] + 1e-5f) * L2E;

  const float4* p0 = (const float4*)&w[(cin0 * 64 + cout) * 16];
  const float4* p1 = (const float4*)&w[((cin0 + 1) * 64 + cout) * 16];
  float a[16], b[16];
  {
    float4 f0 = p0[0], f1 = p0[1], f2 = p0[2], f3 = p0[3];
    a[0]=f0.x; a[1]=f0.y; a[2]=f0.z; a[3]=f0.w; a[4]=f1.x; a[5]=f1.y; a[6]=f1.z; a[7]=f1.w;
    a[8]=f2.x; a[9]=f2.y; a[10]=f2.z; a[11]=f2.w; a[12]=f3.x; a[13]=f3.y; a[14]=f3.z; a[15]=f3.w;
    float4 g0 = p1[0], g1 = p1[1], g2 = p1[2], g3 = p1[3];
    b[0]=g0.x; b[1]=g0.y; b[2]=g0.z; b[3]=g0.w; b[4]=g1.x; b[5]=g1.y; b[6]=g1.z; b[7]=g1.w;
    b[8]=g2.x; b[9]=g2.y; b[10]=g2.z; b[11]=g2.w; b[12]=g3.x; b[13]=g3.y; b[14]=g3.z; b[15]=g3.w;
  }
#pragma unroll
  for (int kh = 0; kh < 4; ++kh)
#pragma unroll
    for (int kw = 0; kw < 4; ++kw) {
      int r = (kh & 1) ? 0 : 1;
      int pp = (kw & 1) ? 0 : 1;
      int c = r * 2 + pp;
      int tap = (kh >> 1) * 2 + (kw >> 1);
      int ks = tap * 2 + ksq;
      unsigned u = (unsigned)f2bf(a[kh * 4 + kw] * Aw) |
                   ((unsigned)f2bf(b[kh * 4 + kw] * Aw) << 16);
      *(unsigned*)&g_wfrag[(((c * 8 + ks) * 4 + nt) * 64 + q * 16 + b15) * 8 + j] = u;
    }

  if (t < 64) {
    float A0 = gamma[t] * rsqrtf(var[t] + 1e-5f);
    g_aff[t] = ((bias[t] - mean[t]) * A0 + beta[t]) * L2E;
  }
}

__device__ __forceinline__ unsigned cvtpk(float a, float b) {
  unsigned r;
  asm("v_cvt_pk_bf16_f32 %0, %1, %2" : "=v"(r) : "v"(a), "v"(b));
  return r;
}

template <int CTRL>
__device__ __forceinline__ float dpp_add(float v) {
  unsigned t = (unsigned)__builtin_amdgcn_update_dpp(
      0, (int)__float_as_uint(v), CTRL, 0xF, 0xF, true);
  return v + __uint_as_float(t);
}

// sum across each 16-lane group, result in all lanes, pure-VALU via DPP.
__device__ __forceinline__ float sum16(float v) {
  v = dpp_add<0xB1>(v);   // quad_perm [1,0,3,2]  (xor 1)
  v = dpp_add<0x4E>(v);   // quad_perm [2,3,0,1]  (xor 2)
  v = dpp_add<0x141>(v);  // row_half_mirror      (xor 4)
  v = dpp_add<0x140>(v);  // row_mirror           (xor 8)
  return v;
}

__device__ __forceinline__ float fexp2(float x) {
#if __has_builtin(__builtin_amdgcn_exp2f)
  return __builtin_amdgcn_exp2f(x);
#else
  return exp2f(x);
#endif
}

#define COLS 66
#define ROWSTRIDE (COLS * 64)  // 4224 ushorts per halo row

__global__ __launch_bounds__(512, 4) void fused_kernel(const float* __restrict__ x,
                                                       float* __restrict__ out) {
  __shared__ __align__(16) ushort xs[4 * ROWSTRIDE];   // 33792 B halo, swizzled
  __shared__ __align__(16) float red[2 * 64 * 65 + 16];  // 33344 B pooled-max, pitch 65

  const int tid  = threadIdx.x;
  // XCD-grouping: consecutive ph-pairs (sharing halo rows) -> same XCD L2
  const int swz  = ((blockIdx.x & 7) << 2) | (blockIdx.x >> 3);  // bijective on [0,32)
  const int ph0  = swz * 2;
  const int n    = blockIdx.y;
  const int wave = tid >> 6;
  const int lane = tid & 63;
  const int b15  = lane & 15;
  const int q    = lane >> 4;
  const int wc   = wave & 1;   // col half (32 cols)
  const int c    = wave >> 1;  // parity class (r,p)
  const int r    = c >> 1, p = c & 1;

  // ---- issue ks=0 weight loads first: L2 latency hides under halo staging ----
  short8 bfA[4], bfB[4];
  {
    const short8* wf = (const short8*)g_wfrag + (c * 8) * 256;
#pragma unroll
    for (int nt = 0; nt < 4; ++nt) bfA[nt] = wf[nt * 64 + lane];
  }

  // ---- zero pooled-max buffer (covered by the staging barrier) ----
  {
    float4 z = {0.f, 0.f, 0.f, 0.f};
    for (int e = tid; e < 2084; e += 512) ((float4*)red)[e] = z;
  }

  // ---- stage x halo rows ph0-1..ph0+2, swizzled [row][col+1][chunk^(col&7)] ----
  for (int e = tid; e < 1024; e += 512) {
    int iw4 = e & 15;          // group of 4 iw
    int c4  = (e >> 4) & 15;   // group of 4 cin
    int row = e >> 8;          // 0..3
    int ih  = ph0 - 1 + row;
    float4 v0 = {0.f, 0.f, 0.f, 0.f}, v1 = v0, v2 = v0, v3 = v0;
    if (ih >= 0 && ih < 64) {
      const float* xp = x + ((n * 64 + c4 * 4) * 64 + ih) * 64 + iw4 * 4;
      v0 = *(const float4*)xp;          v1 = *(const float4*)(xp + 4096);
      v2 = *(const float4*)(xp + 8192); v3 = *(const float4*)(xp + 12288);
    }
    int chunk = c4 >> 1, half4 = (c4 & 1) * 4;
    float cc[4][4] = {{v0.x, v1.x, v2.x, v3.x}, {v0.y, v1.y, v2.y, v3.y},
                      {v0.z, v1.z, v2.z, v3.z}, {v0.w, v1.w, v2.w, v3.w}};
#pragma unroll
    for (int ii = 0; ii < 4; ++ii) {
      int col = iw4 * 4 + ii + 1;
      uint2v pk = {cvtpk(cc[ii][0], cc[ii][1]), cvtpk(cc[ii][2], cc[ii][3])};
      *(uint2v*)&xs[(row * COLS + col) * 64 + ((chunk ^ (col & 7)) * 8) + half4] = pk;
    }
  }
  // zero-pad cols 0 and 65 (all 4 rows, all chunks)
  for (int e = tid; e < 128; e += 512) {
    int c4 = e & 15, side = (e >> 4) & 1, row = e >> 5;
    int col = side ? 65 : 0;
    int chunk = c4 >> 1, half4 = (c4 & 1) * 4;
    ushort4 z; z.x = z.y = z.z = z.w = 0;
    *(ushort4*)&xs[(row * COLS + col) * 64 + ((chunk ^ (col & 7)) * 8) + half4] = z;
  }

  // BN bias (already * log2e) -> MFMA C-in
  float Dc[4];
#pragma unroll
  for (int nt = 0; nt < 4; ++nt) Dc[nt] = g_aff[nt * 16 + b15];

  // a-frag base addresses A2[b][par] (mt 0, prow 0, a=1 row); mt (+1024 ushort),
  // prow/a (+ROWSTRIDE) are compile-time immediates on the ds_read.
  int A2[2][2];
#pragma unroll
  for (int b = 0; b < 2; ++b) {
    int col = wc * 32 + b15 + (b ? p - 1 : p) + 1;  // 0..65 (mt=0)
#pragma unroll
    for (int par = 0; par < 2; ++par)
      A2[b][par] = r * ROWSTRIDE + col * 64 + (((par * 4 + q) ^ (col & 7)) * 8);
  }

  __syncthreads();  // halo + red-zero complete

  floatx4 acc[16];  // [prow*8 + mt*4 + nt], C-in = BN bias
#pragma unroll
  for (int i = 0; i < 16; ++i) {
    float d = Dc[i & 3];
    acc[i] = (floatx4){d, d, d, d};
  }

#pragma unroll
  for (int ks = 0; ks < 8; ++ks) {
    short8* bcur = (ks & 1) ? bfB : bfA;
    short8* bnxt = (ks & 1) ? bfA : bfB;
    if (ks < 7) {  // prefetch next ks's weights (in flight across 16 MFMAs)
      const short8* wf = (const short8*)g_wfrag + (c * 8 + ks + 1) * 256;
#pragma unroll
      for (int nt = 0; nt < 4; ++nt) bnxt[nt] = wf[nt * 64 + lane];
    }
    const int b_ = (ks >> 1) & 1, par_ = ks & 1;
    const int ro = (ks >> 2) ? 0 : ROWSTRIDE;  // (1-a)*RS
    const int base = A2[b_][par_] + ro;
    short8 af00 = *(const short8*)&xs[base];                     // prow0 mt0
    short8 af01 = *(const short8*)&xs[base + 1024];              // prow0 mt1
    short8 af10 = *(const short8*)&xs[base + ROWSTRIDE];         // prow1 mt0
    short8 af11 = *(const short8*)&xs[base + ROWSTRIDE + 1024];  // prow1 mt1
#pragma unroll
    for (int nt = 0; nt < 4; ++nt) {
      acc[nt]      = __builtin_amdgcn_mfma_f32_16x16x32_bf16(af00, bcur[nt], acc[nt], 0, 0, 0);
      acc[4 + nt]  = __builtin_amdgcn_mfma_f32_16x16x32_bf16(af01, bcur[nt], acc[4 + nt], 0, 0, 0);
      acc[8 + nt]  = __builtin_amdgcn_mfma_f32_16x16x32_bf16(af10, bcur[nt], acc[8 + nt], 0, 0, 0);
      acc[12 + nt] = __builtin_amdgcn_mfma_f32_16x16x32_bf16(af11, bcur[nt], acc[12 + nt], 0, 0, 0);
    }
  }

  // ---- softmax (exp2 of pre-scaled logits) + cross-class maxpool via ds_max_u32 ----
  // (no barrier needed: red zeroed before the staging barrier; atomics order-free)
#pragma unroll
  for (int prow = 0; prow < 2; ++prow)
#pragma unroll
    for (int mt = 0; mt < 2; ++mt) {
      float sm[4] = {0.f, 0.f, 0.f, 0.f};
#pragma unroll
      for (int nt = 0; nt < 4; ++nt)
#pragma unroll
        for (int reg = 0; reg < 4; ++reg) {
          float e = fexp2(acc[prow * 8 + mt * 4 + nt][reg]);
          acc[prow * 8 + mt * 4 + nt][reg] = e;
          sm[reg] += e;
        }
#pragma unroll
      for (int reg = 0; reg < 4; ++reg)
        sm[reg] = __builtin_amdgcn_rcpf(sum16(sm[reg]));
#pragma unroll
      for (int nt = 0; nt < 4; ++nt) {
        int idx = (prow * 64 + nt * 16 + b15) * 65 + wc * 32 + mt * 16 + q * 4;
#pragma unroll
        for (int reg = 0; reg < 4; ++reg) {
          float v = acc[prow * 8 + mt * 4 + nt][reg] * sm[reg];
          __hip_atomic_fetch_max((unsigned*)&red[idx + reg], __float_as_uint(v),
                                 __ATOMIC_RELAXED, __HIP_MEMORY_SCOPE_WORKGROUP);
        }
      }
    }
  __syncthreads();

  // ---- coalesced stores ----
  for (int e = tid; e < 4096; e += 512) {
    int pw2  = e & 31;
    int cout = (e >> 5) & 63;
    int rl   = e >> 11;
    int base = (rl * 64 + cout) * 65 + pw2 * 2;
    float2 val = {red[base], red[base + 1]};
    *(float2*)&out[((n * 64 + cout) * 64 + (ph0 + rl)) * 64 + pw2 * 2] = val;
  }
}

extern "C" void kernel_launch(void* const* d_in, const int* in_sizes, int n_in,
                              void* d_out, int out_size, void* d_ws, size_t ws_size,
                              hipStream_t stream) {
  const float* x     = (const float*)d_in[0];
  const float* w     = (const float*)d_in[1];
  const float* bias  = (const float*)d_in[2];
  const float* gamma = (const float*)d_in[3];
  const float* beta  = (const float*)d_in[4];
  const float* mean  = (const float*)d_in[5];
  const float* var   = (const float*)d_in[6];
  float* out = (float*)d_out;

  prep_kernel<<<8, 256, 0, stream>>>(w, bias, gamma, beta, mean, var);
  dim3 grid(32, 32);  // (pooled-row pair [XCD-swizzled], n)
  fused_kernel<<<grid, 512, 0, stream>>>(x, out);
}

// Round 10
// 117.839 us; speedup vs baseline: 1.0603x; 1.0603x over previous
//
#include <hip/hip_runtime.h>
#include <hip/hip_bf16.h>
#include <math.h>

// Fused ConvTranspose2d(64->64,k4,s2,p1) + BN + softmax(C) + maxpool2x2 via bf16 MFMA.
//
// R17: barrier-free ks loop WITHOUT register weights (R16's register-weight
// attempt spilled: acc[16]+bf[32] > 128-reg cap -> 40MB scratch, 45us).
//  - per-wave-PRIVATE LDS weight segments: wave (c,wc) double-buffers its
//    class's 4 nt-segments (4KB) via global_load_lds into wbuf[buf][wave].
//    All hazards wave-local: read-after-stage = own vmcnt(0) (inline asm,
//    no barrier); overwrite-after-read = own lgkm ordering + >=225cy DMA
//    flight. In-loop barriers: 8 (R15) -> 0; total 2 per block.
//  - no bf VGPRs -> acc[16]+af+addr ~= 100 regs; launch_bounds(512,2)
//    (256-reg cap) -> zero spill risk.
//  - L2 weight traffic 128->256MB (no wave-pair sharing), hidden under
//    16 MFMAs/ks (~310cy > ~225cy L2 latency).
//  - LDS = 33792(xs) + 65536(wbuf) + 33344(red) = 132672 -> 1 block/CU
//    (AITER fmha precedent: 160KB/workgroup allocates on gfx950).
//    Grid 1024 = 4 clean generations of 256 CUs.
// Kept: 2 pooled rows/block, class-per-wave, pitch-65 ds_max_u32 pooling,
// XCD-grouping swizzle, BN bias as MFMA C-in, log2e folded into weights,
// padded 66-col halo, DPP 16-lane softmax reduce, cvt_pk staging.

typedef __attribute__((ext_vector_type(8))) short short8;
typedef __attribute__((ext_vector_type(4))) float floatx4;
typedef __attribute__((ext_vector_type(2))) unsigned uint2v;

__device__ ushort g_wfrag[4 * 8 * 4 * 64 * 8];  // [class][ks][nt][lane][j], 128 KB
__device__ float g_aff[64];  // ((bias-mean)*A + beta) * log2e

#define L2E 1.44269504088896340736f

__device__ __forceinline__ ushort f2bf(float f) {
  union { float f; unsigned u; } v; v.f = f;
  unsigned r = v.u + 0x7FFF + ((v.u >> 16) & 1);  // RNE
  return (ushort)(r >> 16);
}

// prep: thread = (cin pair, cout). BN scale A and log2(e) folded into weights.
__global__ __launch_bounds__(256) void prep_kernel(
    const float* __restrict__ w, const float* __restrict__ bias,
    const float* __restrict__ gamma, const float* __restrict__ beta,
    const float* __restrict__ mean, const float* __restrict__ var) {
  int t = blockIdx.x * 256 + threadIdx.x;  // 0..2047
  int cin0 = (t >> 6) * 2;                 // even cin
  int cout = t & 63;
  int nt = cout >> 4, b15 = cout & 15;
  int q = (cin0 & 31) >> 3;                // quad within k-step
  int j = cin0 & 7;                        // j within quad (even)
  int ksq = cin0 >> 5;                     // which 32-block within tap
  float Aw = gamma[cout] * rsqrtf(var[cout] + 1e-5f) * L2E;

  const float4* p0 = (const float4*)&w[(cin0 * 64 + cout) * 16];
  const float4* p1 = (const float4*)&w[((cin0 + 1) * 64 + cout) * 16];
  float a[16], b[16];
  {
    float4 f0 = p0[0], f1 = p0[1], f2 = p0[2], f3 = p0[3];
    a[0]=f0.x; a[1]=f0.y; a[2]=f0.z; a[3]=f0.w; a[4]=f1.x; a[5]=f1.y; a[6]=f1.z; a[7]=f1.w;
    a[8]=f2.x; a[9]=f2.y; a[10]=f2.z; a[11]=f2.w; a[12]=f3.x; a[13]=f3.y; a[14]=f3.z; a[15]=f3.w;
    float4 g0 = p1[0], g1 = p1[1], g2 = p1[2], g3 = p1[3];
    b[0]=g0.x; b[1]=g0.y; b[2]=g0.z; b[3]=g0.w; b[4]=g1.x; b[5]=g1.y; b[6]=g1.z; b[7]=g1.w;
    b[8]=g2.x; b[9]=g2.y; b[10]=g2.z; b[11]=g2.w; b[12]=g3.x; b[13]=g3.y; b[14]=g3.z; b[15]=g3.w;
  }
#pragma unroll
  for (int kh = 0; kh < 4; ++kh)
#pragma unroll
    for (int kw = 0; kw < 4; ++kw) {
      int r = (kh & 1) ? 0 : 1;
      int pp = (kw & 1) ? 0 : 1;
      int c = r * 2 + pp;
      int tap = (kh >> 1) * 2 + (kw >> 1);
      int ks = tap * 2 + ksq;
      unsigned u = (unsigned)f2bf(a[kh * 4 + kw] * Aw) |
                   ((unsigned)f2bf(b[kh * 4 + kw] * Aw) << 16);
      *(unsigned*)&g_wfrag[(((c * 8 + ks) * 4 + nt) * 64 + q * 16 + b15) * 8 + j] = u;
    }

  if (t < 64) {
    float A0 = gamma[t] * rsqrtf(var[t] + 1e-5f);
    g_aff[t] = ((bias[t] - mean[t]) * A0 + beta[t]) * L2E;
  }
}

__device__ __forceinline__ unsigned cvtpk(float a, float b) {
  unsigned r;
  asm("v_cvt_pk_bf16_f32 %0, %1, %2" : "=v"(r) : "v"(a), "v"(b));
  return r;
}

template <int CTRL>
__device__ __forceinline__ float dpp_add(float v) {
  unsigned t = (unsigned)__builtin_amdgcn_update_dpp(
      0, (int)__float_as_uint(v), CTRL, 0xF, 0xF, true);
  return v + __uint_as_float(t);
}

// sum across each 16-lane group, result in all lanes, pure-VALU via DPP.
__device__ __forceinline__ float sum16(float v) {
  v = dpp_add<0xB1>(v);   // quad_perm [1,0,3,2]  (xor 1)
  v = dpp_add<0x4E>(v);   // quad_perm [2,3,0,1]  (xor 2)
  v = dpp_add<0x141>(v);  // row_half_mirror      (xor 4)
  v = dpp_add<0x140>(v);  // row_mirror           (xor 8)
  return v;
}

__device__ __forceinline__ float fexp2(float x) {
#if __has_builtin(__builtin_amdgcn_exp2f)
  return __builtin_amdgcn_exp2f(x);
#else
  return exp2f(x);
#endif
}

__device__ __forceinline__ void gload_lds16(const void* g, void* l) {
  __builtin_amdgcn_global_load_lds(
      (const __attribute__((address_space(1))) void*)g,
      (__attribute__((address_space(3))) void*)l, 16, 0, 0);
}

#define COLS 66
#define ROWSTRIDE (COLS * 64)  // 4224 ushorts per halo row

__global__ __launch_bounds__(512, 2) void fused_kernel(const float* __restrict__ x,
                                                       float* __restrict__ out) {
  __shared__ __align__(16) ushort xs[4 * ROWSTRIDE];      // 33792 B halo, swizzled
  __shared__ __align__(16) ushort wbuf[2 * 8 * 4 * 512];  // 65536 B per-wave weight dbuf
  __shared__ __align__(16) float red[2 * 64 * 65 + 16];   // 33344 B pooled-max, pitch 65

  const int tid  = threadIdx.x;
  // XCD-grouping: consecutive ph-pairs (sharing halo rows) -> same XCD L2
  const int swz  = ((blockIdx.x & 7) << 2) | (blockIdx.x >> 3);  // bijective on [0,32)
  const int ph0  = swz * 2;
  const int n    = blockIdx.y;
  const int wave = tid >> 6;
  const int lane = tid & 63;
  const int b15  = lane & 15;
  const int q    = lane >> 4;
  const int wc   = wave & 1;   // col half (32 cols)
  const int c    = wave >> 1;  // parity class (r,p)
  const int r    = c >> 1, p = c & 1;

  // per-wave private weight staging: wave stages its OWN class's 4 nt segs
#define STAGE_W(buf_, ks_)                                                    \
  {                                                                           \
    _Pragma("unroll")                                                         \
    for (int nt_ = 0; nt_ < 4; ++nt_)                                         \
      gload_lds16(&g_wfrag[(((c * 8 + (ks_)) * 4 + nt_) * 64 + lane) * 8],    \
                  &wbuf[(((buf_)*8 + wave) * 4 + nt_) * 512]);                \
  }
  STAGE_W(0, 0);  // ks=0: L2 latency hides under halo staging

  // ---- zero pooled-max buffer (covered by the staging barrier) ----
  {
    float4 z = {0.f, 0.f, 0.f, 0.f};
    for (int e = tid; e < 2084; e += 512) ((float4*)red)[e] = z;
  }

  // ---- stage x halo rows ph0-1..ph0+2, swizzled [row][col+1][chunk^(col&7)] ----
  for (int e = tid; e < 1024; e += 512) {
    int iw4 = e & 15;          // group of 4 iw
    int c4  = (e >> 4) & 15;   // group of 4 cin
    int row = e >> 8;          // 0..3
    int ih  = ph0 - 1 + row;
    float4 v0 = {0.f, 0.f, 0.f, 0.f}, v1 = v0, v2 = v0, v3 = v0;
    if (ih >= 0 && ih < 64) {
      const float* xp = x + ((n * 64 + c4 * 4) * 64 + ih) * 64 + iw4 * 4;
      v0 = *(const float4*)xp;          v1 = *(const float4*)(xp + 4096);
      v2 = *(const float4*)(xp + 8192); v3 = *(const float4*)(xp + 12288);
    }
    int chunk = c4 >> 1, half4 = (c4 & 1) * 4;
    float cc[4][4] = {{v0.x, v1.x, v2.x, v3.x}, {v0.y, v1.y, v2.y, v3.y},
                      {v0.z, v1.z, v2.z, v3.z}, {v0.w, v1.w, v2.w, v3.w}};
#pragma unroll
    for (int ii = 0; ii < 4; ++ii) {
      int col = iw4 * 4 + ii + 1;
      uint2v pk = {cvtpk(cc[ii][0], cc[ii][1]), cvtpk(cc[ii][2], cc[ii][3])};
      *(uint2v*)&xs[(row * COLS + col) * 64 + ((chunk ^ (col & 7)) * 8) + half4] = pk;
    }
  }
  // zero-pad cols 0 and 65 (all 4 rows, all chunks)
  for (int e = tid; e < 128; e += 512) {
    int c4 = e & 15, side = (e >> 4) & 1, row = e >> 5;
    int col = side ? 65 : 0;
    int chunk = c4 >> 1, half4 = (c4 & 1) * 4;
    ushort4 z; z.x = z.y = z.z = z.w = 0;
    *(ushort4*)&xs[(row * COLS + col) * 64 + ((chunk ^ (col & 7)) * 8) + half4] = z;
  }

  // BN bias (already * log2e) -> MFMA C-in
  float Dc[4];
#pragma unroll
  for (int nt = 0; nt < 4; ++nt) Dc[nt] = g_aff[nt * 16 + b15];

  // a-frag base addresses A2[b][par] (mt 0, prow 0, a=1 row); mt (+1024 ushort),
  // prow/a (+ROWSTRIDE) are compile-time immediates on the ds_read.
  int A2[2][2];
#pragma unroll
  for (int b = 0; b < 2; ++b) {
    int col = wc * 32 + b15 + (b ? p - 1 : p) + 1;  // 0..65 (mt=0)
#pragma unroll
    for (int par = 0; par < 2; ++par)
      A2[b][par] = r * ROWSTRIDE + col * 64 + (((par * 4 + q) ^ (col & 7)) * 8);
  }

  __syncthreads();  // halo + red-zero complete (also drains ks=0 stage)

  floatx4 acc[16];  // [prow*8 + mt*4 + nt], C-in = BN bias
#pragma unroll
  for (int i = 0; i < 16; ++i) {
    float d = Dc[i & 3];
    acc[i] = (floatx4){d, d, d, d};
  }

#pragma unroll
  for (int ks = 0; ks < 8; ++ks) {
    const int cur = ks & 1;
    // own previous stage complete (wave-local; no barrier needed)
    asm volatile("s_waitcnt vmcnt(0)" ::: "memory");
    // weights for this ks from own LDS slot
    short8 bf[4];
#pragma unroll
    for (int nt = 0; nt < 4; ++nt)
      bf[nt] = *(const short8*)&wbuf[((cur * 8 + wave) * 4 + nt) * 512 + lane * 8];
    // a-frags
    const int b_ = (ks >> 1) & 1, par_ = ks & 1;
    const int ro = (ks >> 2) ? 0 : ROWSTRIDE;  // (1-a)*RS
    const int base = A2[b_][par_] + ro;
    short8 af00 = *(const short8*)&xs[base];                     // prow0 mt0
    short8 af01 = *(const short8*)&xs[base + 1024];              // prow0 mt1
    short8 af10 = *(const short8*)&xs[base + ROWSTRIDE];         // prow1 mt0
    short8 af11 = *(const short8*)&xs[base + ROWSTRIDE + 1024];  // prow1 mt1
    // issue next ks's stage (in flight across the MFMAs; wave-local hazard only)
    if (ks < 7) STAGE_W(cur ^ 1, ks + 1);
#pragma unroll
    for (int nt = 0; nt < 4; ++nt) {
      acc[nt]      = __builtin_amdgcn_mfma_f32_16x16x32_bf16(af00, bf[nt], acc[nt], 0, 0, 0);
      acc[4 + nt]  = __builtin_amdgcn_mfma_f32_16x16x32_bf16(af01, bf[nt], acc[4 + nt], 0, 0, 0);
      acc[8 + nt]  = __builtin_amdgcn_mfma_f32_16x16x32_bf16(af10, bf[nt], acc[8 + nt], 0, 0, 0);
      acc[12 + nt] = __builtin_amdgcn_mfma_f32_16x16x32_bf16(af11, bf[nt], acc[12 + nt], 0, 0, 0);
    }
  }

  // ---- softmax (exp2 of pre-scaled logits) + cross-class maxpool via ds_max_u32 ----
  // (no barrier: red zeroed before the staging barrier; atomics order-free)
#pragma unroll
  for (int prow = 0; prow < 2; ++prow)
#pragma unroll
    for (int mt = 0; mt < 2; ++mt) {
      float sm[4] = {0.f, 0.f, 0.f, 0.f};
#pragma unroll
      for (int nt = 0; nt < 4; ++nt)
#pragma unroll
        for (int reg = 0; reg < 4; ++reg) {
          float e = fexp2(acc[prow * 8 + mt * 4 + nt][reg]);
          acc[prow * 8 + mt * 4 + nt][reg] = e;
          sm[reg] += e;
        }
#pragma unroll
      for (int reg = 0; reg < 4; ++reg)
        sm[reg] = __builtin_amdgcn_rcpf(sum16(sm[reg]));
#pragma unroll
      for (int nt = 0; nt < 4; ++nt) {
        int idx = (prow * 64 + nt * 16 + b15) * 65 + wc * 32 + mt * 16 + q * 4;
#pragma unroll
        for (int reg = 0; reg < 4; ++reg) {
          float v = acc[prow * 8 + mt * 4 + nt][reg] * sm[reg];
          __hip_atomic_fetch_max((unsigned*)&red[idx + reg], __float_as_uint(v),
                                 __ATOMIC_RELAXED, __HIP_MEMORY_SCOPE_WORKGROUP);
        }
      }
    }
  __syncthreads();

  // ---- coalesced stores ----
  for (int e = tid; e < 4096; e += 512) {
    int pw2  = e & 31;
    int cout = (e >> 5) & 63;
    int rl   = e >> 11;
    int base = (rl * 64 + cout) * 65 + pw2 * 2;
    float2 val = {red[base], red[base + 1]};
    *(float2*)&out[((n * 64 + cout) * 64 + (ph0 + rl)) * 64 + pw2 * 2] = val;
  }
}

extern "C" void kernel_launch(void* const* d_in, const int* in_sizes, int n_in,
                              void* d_out, int out_size, void* d_ws, size_t ws_size,
                              hipStream_t stream) {
  const float* x     = (const float*)d_in[0];
  const float* w     = (const float*)d_in[1];
  const float* bias  = (const float*)d_in[2];
  const float* gamma = (const float*)d_in[3];
  const float* beta  = (const float*)d_in[4];
  const float* mean  = (const float*)d_in[5];
  const float* var   = (const float*)d_in[6];
  float* out = (float*)d_out;

  prep_kernel<<<8, 256, 0, stream>>>(w, bias, gamma, beta, mean, var);
  dim3 grid(32, 32);  // (pooled-row pair [XCD-swizzled], n)
  fused_kernel<<<grid, 512, 0, stream>>>(x, out);
}

// Round 11
// 113.329 us; speedup vs baseline: 1.1025x; 1.0398x over previous
//
#include <hip/hip_runtime.h>
#include <hip/hip_bf16.h>
#include <math.h>

// Fused ConvTranspose2d(64->64,k4,s2,p1) + BN + softmax(C) + maxpool2x2 via bf16 MFMA.
//
// R18 = R15's occupancy (2 blocks/CU) + R17's barrier-free ks loop:
//  - per-wave-PRIVATE single-buffer wbuf (8 waves x 4 nt x 1KB = 32KB)
//    OVERLAID on red (33344B; wbuf dead before red first written).
//    LDS = 33792(xs) + 33344(red/wbuf) = 67136 -> 2 blocks/CU.
//  - ks loop, zero barriers: vmcnt(0) [own stage done] -> bf+af ds_reads ->
//    lgkmcnt(0) [reads retired] -> STAGE(ks+1) into same slot (safe) ->
//    16 MFMAs (~310cy) hide the ~225cy DMA.
//  - no red zeroing: class-0 waves ds_write their softmax results (cover
//    every slot exactly once); classes 1-3 atomic-max after one barrier.
//    DS ops 2084+16384 -> 4096+12288. Softmax (reg-only) BEFORE the
//    post-loop barrier to overlap with laggard waves.
//  - barriers/block: 11 (R15) -> 4. launch_bounds(512,4): VGPR<=64 +
//    64 AGPR acc = 128 (R15-proven fit; R16/R11 spills were bf[32]-driven).
// Kept: 2 prow/block, class-per-wave, pitch-65 red, XCD swizzle, BN bias
// as MFMA C-in, log2e in weights, padded 66-col halo, DPP sum16, cvt_pk.

typedef __attribute__((ext_vector_type(8))) short short8;
typedef __attribute__((ext_vector_type(4))) float floatx4;
typedef __attribute__((ext_vector_type(2))) unsigned uint2v;

__device__ ushort g_wfrag[4 * 8 * 4 * 64 * 8];  // [class][ks][nt][lane][j], 128 KB
__device__ float g_aff[64];  // ((bias-mean)*A + beta) * log2e

#define L2E 1.44269504088896340736f

__device__ __forceinline__ ushort f2bf(float f) {
  union { float f; unsigned u; } v; v.f = f;
  unsigned r = v.u + 0x7FFF + ((v.u >> 16) & 1);  // RNE
  return (ushort)(r >> 16);
}

// prep: thread = (cin pair, cout). BN scale A and log2(e) folded into weights.
__global__ __launch_bounds__(256) void prep_kernel(
    const float* __restrict__ w, const float* __restrict__ bias,
    const float* __restrict__ gamma, const float* __restrict__ beta,
    const float* __restrict__ mean, const float* __restrict__ var) {
  int t = blockIdx.x * 256 + threadIdx.x;  // 0..2047
  int cin0 = (t >> 6) * 2;                 // even cin
  int cout = t & 63;
  int nt = cout >> 4, b15 = cout & 15;
  int q = (cin0 & 31) >> 3;                // quad within k-step
  int j = cin0 & 7;                        // j within quad (even)
  int ksq = cin0 >> 5;                     // which 32-block within tap
  float Aw = gamma[cout] * rsqrtf(var[cout] + 1e-5f) * L2E;

  const float4* p0 = (const float4*)&w[(cin0 * 64 + cout) * 16];
  const float4* p1 = (const float4*)&w[((cin0 + 1) * 64 + cout) * 16];
  float a[16], b[16];
  {
    float4 f0 = p0[0], f1 = p0[1], f2 = p0[2], f3 = p0[3];
    a[0]=f0.x; a[1]=f0.y; a[2]=f0.z; a[3]=f0.w; a[4]=f1.x; a[5]=f1.y; a[6]=f1.z; a[7]=f1.w;
    a[8]=f2.x; a[9]=f2.y; a[10]=f2.z; a[11]=f2.w; a[12]=f3.x; a[13]=f3.y; a[14]=f3.z; a[15]=f3.w;
    float4 g0 = p1[0], g1 = p1[1], g2 = p1[2], g3 = p1[3];
    b[0]=g0.x; b[1]=g0.y; b[2]=g0.z; b[3]=g0.w; b[4]=g1.x; b[5]=g1.y; b[6]=g1.z; b[7]=g1.w;
    b[8]=g2.x; b[9]=g2.y; b[10]=g2.z; b[11]=g2.w; b[12]=g3.x; b[13]=g3.y; b[14]=g3.z; b[15]=g3.w;
  }
#pragma unroll
  for (int kh = 0; kh < 4; ++kh)
#pragma unroll
    for (int kw = 0; kw < 4; ++kw) {
      int r = (kh & 1) ? 0 : 1;
      int pp = (kw & 1) ? 0 : 1;
      int c = r * 2 + pp;
      int tap = (kh >> 1) * 2 + (kw >> 1);
      int ks = tap * 2 + ksq;
      unsigned u = (unsigned)f2bf(a[kh * 4 + kw] * Aw) |
                   ((unsigned)f2bf(b[kh * 4 + kw] * Aw) << 16);
      *(unsigned*)&g_wfrag[(((c * 8 + ks) * 4 + nt) * 64 + q * 16 + b15) * 8 + j] = u;
    }

  if (t < 64) {
    float A0 = gamma[t] * rsqrtf(var[t] + 1e-5f);
    g_aff[t] = ((bias[t] - mean[t]) * A0 + beta[t]) * L2E;
  }
}

__device__ __forceinline__ unsigned cvtpk(float a, float b) {
  unsigned r;
  asm("v_cvt_pk_bf16_f32 %0, %1, %2" : "=v"(r) : "v"(a), "v"(b));
  return r;
}

template <int CTRL>
__device__ __forceinline__ float dpp_add(float v) {
  unsigned t = (unsigned)__builtin_amdgcn_update_dpp(
      0, (int)__float_as_uint(v), CTRL, 0xF, 0xF, true);
  return v + __uint_as_float(t);
}

// sum across each 16-lane group, result in all lanes, pure-VALU via DPP.
__device__ __forceinline__ float sum16(float v) {
  v = dpp_add<0xB1>(v);   // quad_perm [1,0,3,2]  (xor 1)
  v = dpp_add<0x4E>(v);   // quad_perm [2,3,0,1]  (xor 2)
  v = dpp_add<0x141>(v);  // row_half_mirror      (xor 4)
  v = dpp_add<0x140>(v);  // row_mirror           (xor 8)
  return v;
}

__device__ __forceinline__ float fexp2(float x) {
#if __has_builtin(__builtin_amdgcn_exp2f)
  return __builtin_amdgcn_exp2f(x);
#else
  return exp2f(x);
#endif
}

__device__ __forceinline__ void gload_lds16(const void* g, void* l) {
  __builtin_amdgcn_global_load_lds(
      (const __attribute__((address_space(1))) void*)g,
      (__attribute__((address_space(3))) void*)l, 16, 0, 0);
}

#define COLS 66
#define ROWSTRIDE (COLS * 64)  // 4224 ushorts per halo row

__global__ __launch_bounds__(512, 4) void fused_kernel(const float* __restrict__ x,
                                                       float* __restrict__ out) {
  __shared__ __align__(16) ushort xs[4 * ROWSTRIDE];    // 33792 B halo, swizzled
  __shared__ __align__(16) float red[2 * 64 * 65 + 16];  // 33344 B; first 32KB = wbuf

  ushort* wbuf = (ushort*)red;  // [wave][nt][512] single-buffer, per-wave private

  const int tid  = threadIdx.x;
  // XCD-grouping: consecutive ph-pairs (sharing halo rows) -> same XCD L2
  const int swz  = ((blockIdx.x & 7) << 2) | (blockIdx.x >> 3);  // bijective on [0,32)
  const int ph0  = swz * 2;
  const int n    = blockIdx.y;
  const int wave = tid >> 6;
  const int lane = tid & 63;
  const int b15  = lane & 15;
  const int q    = lane >> 4;
  const int wc   = wave & 1;   // col half (32 cols)
  const int c    = wave >> 1;  // parity class (r,p)
  const int r    = c >> 1, p = c & 1;

  // per-wave private weight staging into the single buffer
#define STAGE_W(ks_)                                                          \
  {                                                                           \
    _Pragma("unroll")                                                         \
    for (int nt_ = 0; nt_ < 4; ++nt_)                                         \
      gload_lds16(&g_wfrag[(((c * 8 + (ks_)) * 4 + nt_) * 64 + lane) * 8],    \
                  &wbuf[(wave * 4 + nt_) * 512]);                             \
  }
  STAGE_W(0);  // ks=0: L2 latency hides under halo staging

  // ---- stage x halo rows ph0-1..ph0+2, swizzled [row][col+1][chunk^(col&7)] ----
  for (int e = tid; e < 1024; e += 512) {
    int iw4 = e & 15;          // group of 4 iw
    int c4  = (e >> 4) & 15;   // group of 4 cin
    int row = e >> 8;          // 0..3
    int ih  = ph0 - 1 + row;
    float4 v0 = {0.f, 0.f, 0.f, 0.f}, v1 = v0, v2 = v0, v3 = v0;
    if (ih >= 0 && ih < 64) {
      const float* xp = x + ((n * 64 + c4 * 4) * 64 + ih) * 64 + iw4 * 4;
      v0 = *(const float4*)xp;          v1 = *(const float4*)(xp + 4096);
      v2 = *(const float4*)(xp + 8192); v3 = *(const float4*)(xp + 12288);
    }
    int chunk = c4 >> 1, half4 = (c4 & 1) * 4;
    float cc[4][4] = {{v0.x, v1.x, v2.x, v3.x}, {v0.y, v1.y, v2.y, v3.y},
                      {v0.z, v1.z, v2.z, v3.z}, {v0.w, v1.w, v2.w, v3.w}};
#pragma unroll
    for (int ii = 0; ii < 4; ++ii) {
      int col = iw4 * 4 + ii + 1;
      uint2v pk = {cvtpk(cc[ii][0], cc[ii][1]), cvtpk(cc[ii][2], cc[ii][3])};
      *(uint2v*)&xs[(row * COLS + col) * 64 + ((chunk ^ (col & 7)) * 8) + half4] = pk;
    }
  }
  // zero-pad cols 0 and 65 (all 4 rows, all chunks)
  for (int e = tid; e < 128; e += 512) {
    int c4 = e & 15, side = (e >> 4) & 1, row = e >> 5;
    int col = side ? 65 : 0;
    int chunk = c4 >> 1, half4 = (c4 & 1) * 4;
    ushort4 z; z.x = z.y = z.z = z.w = 0;
    *(ushort4*)&xs[(row * COLS + col) * 64 + ((chunk ^ (col & 7)) * 8) + half4] = z;
  }

  // BN bias (already * log2e) -> MFMA C-in
  float Dc[4];
#pragma unroll
  for (int nt = 0; nt < 4; ++nt) Dc[nt] = g_aff[nt * 16 + b15];

  // a-frag base addresses A2[b][par] (mt 0, prow 0, a=1 row); mt (+1024 ushort),
  // prow/a (+ROWSTRIDE) are compile-time immediates on the ds_read.
  int A2[2][2];
#pragma unroll
  for (int b = 0; b < 2; ++b) {
    int col = wc * 32 + b15 + (b ? p - 1 : p) + 1;  // 0..65 (mt=0)
#pragma unroll
    for (int par = 0; par < 2; ++par)
      A2[b][par] = r * ROWSTRIDE + col * 64 + (((par * 4 + q) ^ (col & 7)) * 8);
  }

  __syncthreads();  // (1) halo complete; ks=0 stage also drained by barrier

  floatx4 acc[16];  // [prow*8 + mt*4 + nt], C-in = BN bias
#pragma unroll
  for (int i = 0; i < 16; ++i) {
    float d = Dc[i & 3];
    acc[i] = (floatx4){d, d, d, d};
  }

#pragma unroll
  for (int ks = 0; ks < 8; ++ks) {
    // own previous stage complete (wave-local; no barrier)
    asm volatile("s_waitcnt vmcnt(0)" ::: "memory");
    short8 bf[4];
#pragma unroll
    for (int nt = 0; nt < 4; ++nt)
      bf[nt] = *(const short8*)&wbuf[(wave * 4 + nt) * 512 + lane * 8];
    const int b_ = (ks >> 1) & 1, par_ = ks & 1;
    const int ro = (ks >> 2) ? 0 : ROWSTRIDE;  // (1-a)*RS
    const int base = A2[b_][par_] + ro;
    short8 af00 = *(const short8*)&xs[base];                     // prow0 mt0
    short8 af01 = *(const short8*)&xs[base + 1024];              // prow0 mt1
    short8 af10 = *(const short8*)&xs[base + ROWSTRIDE];         // prow1 mt0
    short8 af11 = *(const short8*)&xs[base + ROWSTRIDE + 1024];  // prow1 mt1
    // reads retired -> safe to overwrite the slot with next ks's weights
    asm volatile("s_waitcnt lgkmcnt(0)" ::: "memory");
    if (ks < 7) STAGE_W(ks + 1);  // in flight across the MFMAs
#pragma unroll
    for (int nt = 0; nt < 4; ++nt) {
      acc[nt]      = __builtin_amdgcn_mfma_f32_16x16x32_bf16(af00, bf[nt], acc[nt], 0, 0, 0);
      acc[4 + nt]  = __builtin_amdgcn_mfma_f32_16x16x32_bf16(af01, bf[nt], acc[4 + nt], 0, 0, 0);
      acc[8 + nt]  = __builtin_amdgcn_mfma_f32_16x16x32_bf16(af10, bf[nt], acc[8 + nt], 0, 0, 0);
      acc[12 + nt] = __builtin_amdgcn_mfma_f32_16x16x32_bf16(af11, bf[nt], acc[12 + nt], 0, 0, 0);
    }
  }

  // ---- softmax in registers (before barrier: overlaps laggard waves' MFMAs) ----
#pragma unroll
  for (int prow = 0; prow < 2; ++prow)
#pragma unroll
    for (int mt = 0; mt < 2; ++mt) {
      float sm[4] = {0.f, 0.f, 0.f, 0.f};
#pragma unroll
      for (int nt = 0; nt < 4; ++nt)
#pragma unroll
        for (int reg = 0; reg < 4; ++reg) {
          float e = fexp2(acc[prow * 8 + mt * 4 + nt][reg]);
          acc[prow * 8 + mt * 4 + nt][reg] = e;
          sm[reg] += e;
        }
#pragma unroll
      for (int reg = 0; reg < 4; ++reg)
        sm[reg] = __builtin_amdgcn_rcpf(sum16(sm[reg]));
#pragma unroll
      for (int nt = 0; nt < 4; ++nt)
#pragma unroll
        for (int reg = 0; reg < 4; ++reg)
          acc[prow * 8 + mt * 4 + nt][reg] *= sm[reg];  // final probabilities
    }

  __syncthreads();  // (2) all waves done with wbuf region -> red may be written

  // ---- cross-class maxpool: class 0 writes (covers every slot once), then
  //      classes 1-3 atomic-max (ds_max_u32 on float bits; values > 0) ----
  if (c == 0) {
#pragma unroll
    for (int prow = 0; prow < 2; ++prow)
#pragma unroll
      for (int mt = 0; mt < 2; ++mt)
#pragma unroll
        for (int nt = 0; nt < 4; ++nt) {
          int idx = (prow * 64 + nt * 16 + b15) * 65 + wc * 32 + mt * 16 + q * 4;
#pragma unroll
          for (int reg = 0; reg < 4; ++reg)
            red[idx + reg] = acc[prow * 8 + mt * 4 + nt][reg];
        }
  }
  __syncthreads();  // (3) class-0 baseline visible
  if (c != 0) {
#pragma unroll
    for (int prow = 0; prow < 2; ++prow)
#pragma unroll
      for (int mt = 0; mt < 2; ++mt)
#pragma unroll
        for (int nt = 0; nt < 4; ++nt) {
          int idx = (prow * 64 + nt * 16 + b15) * 65 + wc * 32 + mt * 16 + q * 4;
#pragma unroll
          for (int reg = 0; reg < 4; ++reg)
            __hip_atomic_fetch_max((unsigned*)&red[idx + reg],
                                   __float_as_uint(acc[prow * 8 + mt * 4 + nt][reg]),
                                   __ATOMIC_RELAXED, __HIP_MEMORY_SCOPE_WORKGROUP);
        }
  }
  __syncthreads();  // (4) pooled max complete

  // ---- coalesced stores ----
  for (int e = tid; e < 4096; e += 512) {
    int pw2  = e & 31;
    int cout = (e >> 5) & 63;
    int rl   = e >> 11;
    int base = (rl * 64 + cout) * 65 + pw2 * 2;
    float2 val = {red[base], red[base + 1]};
    *(float2*)&out[((n * 64 + cout) * 64 + (ph0 + rl)) * 64 + pw2 * 2] = val;
  }
}

extern "C" void kernel_launch(void* const* d_in, const int* in_sizes, int n_in,
                              void* d_out, int out_size, void* d_ws, size_t ws_size,
                              hipStream_t stream) {
  const float* x     = (const float*)d_in[0];
  const float* w     = (const float*)d_in[1];
  const float* bias  = (const float*)d_in[2];
  const float* gamma = (const float*)d_in[3];
  const float* beta  = (const float*)d_in[4];
  const float* mean  = (const float*)d_in[5];
  const float* var   = (const float*)d_in[6];
  float* out = (float*)d_out;

  prep_kernel<<<8, 256, 0, stream>>>(w, bias, gamma, beta, mean, var);
  dim3 grid(32, 32);  // (pooled-row pair [XCD-swizzled], n)
  fused_kernel<<<grid, 512, 0, stream>>>(x, out);
}